// Round 10
// baseline (119.931 us; speedup 1.0000x reference)
//
#include <hip/hip_runtime.h>
#include <cstdint>
#include <cstddef>

#define CLS 512
#define NBINS 10
#define ROWS_PER_BLOCK 64      // 4 waves x 16 rows
#define FXSCALE 16777216.0f    // 2^24 fixed-point scale for ce*cnt
#define LOG513 6.2402782f      // ln(513)
#define SLOTS 64               // global histogram copies (atomic spreading)
#define HSTRIDE 32             // u32 per slot (128 B line)
#define DSTRIDE 16             // u64 per slot (128 B line)

// ws layout: [ uint32 H[SLOTS][HSTRIDE] (8 KB) | uint64 Dq[SLOTS][DSTRIDE] (8 KB) | uint32 done ]

__global__ __launch_bounds__(256) void ghm_init_kernel(unsigned int* __restrict__ H,
                                                       unsigned long long* __restrict__ Dq,
                                                       unsigned int* __restrict__ done) {
    for (int k = threadIdx.x; k < SLOTS * HSTRIDE; k += 256) H[k] = 0u;
    for (int k = threadIdx.x; k < SLOTS * DSTRIDE; k += 256) Dq[k] = 0ull;
    if (threadIdx.x == 0) *done = 0u;
}

// One wave per row, 16 rows/wave, prefetch depth 2.
// NOTE on launch bounds: plain (256) ONLY. Adding a min-waves-per-EU arg
// (R8: (256,8), R9: (256,4)) puts the scheduler in pressure-min mode, which
// sinks the prefetch loads to their uses -- pipeline destroyed, kernel goes
// latency-bound at ~2x duration (VGPR 32/36, L3-resident replays equally
// slow). Keep the allocator free (VGPR ~44-52, pipelined schedule).
__global__ __launch_bounds__(256) void ghm_main_kernel(const float* __restrict__ pred,
                                                       const int* __restrict__ target,
                                                       unsigned int* __restrict__ H,
                                                       unsigned long long* __restrict__ Dq,
                                                       unsigned int* __restrict__ done,
                                                       float* __restrict__ out,
                                                       int nrows) {
    __shared__ unsigned int sH[NBINS];
    __shared__ unsigned long long sD[NBINS];
    __shared__ int isLast;
    if (threadIdx.x < NBINS) { sH[threadIdx.x] = 0u; sD[threadIdx.x] = 0ull; }
    __syncthreads();

    const int lane = threadIdx.x & 63;
    const int wid  = threadIdx.x >> 6;
    const int base = blockIdx.x * ROWS_PER_BLOCK;

    // per-wave fast-path accumulators (flushed once at the end)
    unsigned int nfast = 0u;
    float dfast = 0.0f;

    // prefetch rows k and k+1 (depth 2)
    float4 a0 = make_float4(0.f, 0.f, 0.f, 0.f), b0 = a0;
    float4 a1 = a0, b1 = a0;
    if (base + wid < nrows) {
        const float4* pr = reinterpret_cast<const float4*>(pred + (size_t)(base + wid) * CLS);
        a0 = pr[lane];
        b0 = pr[lane + 64];
    }
    if (base + wid + 4 < nrows) {
        const float4* pr = reinterpret_cast<const float4*>(pred + (size_t)(base + wid + 4) * CLS);
        a1 = pr[lane];
        b1 = pr[lane + 64];
    }

    for (int rr = wid; rr < ROWS_PER_BLOCK; rr += 4) {
        const int row = base + rr;
        if (row >= nrows) break;

        // issue row k+2's loads before computing on row k
        float4 a2 = make_float4(0.f, 0.f, 0.f, 0.f), b2 = a2;
        if (rr + 8 < ROWS_PER_BLOCK && row + 8 < nrows) {
            const float4* pn = reinterpret_cast<const float4*>(pred + (size_t)(row + 8) * CLS);
            a2 = pn[lane];
            b2 = pn[lane + 64];
        }

        // direct exp (no max subtraction; inputs N(0,1), |x| < ~6, finite in f32)
        float e[8];
        e[0] = __expf(a0.x); e[1] = __expf(a0.y); e[2] = __expf(a0.z); e[3] = __expf(a0.w);
        e[4] = __expf(b0.x); e[5] = __expf(b0.y); e[6] = __expf(b0.z); e[7] = __expf(b0.w);

        // lane-local sum + max trees (interleaved ILP)
        float s01 = e[0] + e[1], s23 = e[2] + e[3], s45 = e[4] + e[5], s67 = e[6] + e[7];
        float m01 = fmaxf(e[0], e[1]), m23 = fmaxf(e[2], e[3]);
        float m45 = fmaxf(e[4], e[5]), m67 = fmaxf(e[6], e[7]);
        float sl = (s01 + s23) + (s45 + s67);
        float ml = fmaxf(fmaxf(m01, m23), fmaxf(m45, m67));

        const int t  = target[row];                 // wave-uniform
        const int tl = (t & 255) >> 2;              // owner lane
        const int te = (t & 3) | ((t >> 8) << 2);   // element 0..7 (uniform)

        // target element of e (uniform select), broadcast from owner lane
        float ca = (te & 4)
            ? ((te & 2) ? ((te & 1) ? e[7] : e[6]) : ((te & 1) ? e[5] : e[4]))
            : ((te & 2) ? ((te & 1) ? e[3] : e[2]) : ((te & 1) ? e[1] : e[0]));
        const float etb = __shfl(ca, tl);           // overlaps with sum ladder

        float s = sl;
#pragma unroll
        for (int o = 32; o > 0; o >>= 1) s += __shfl_xor(s, o);
        const float inv = __builtin_amdgcn_rcpf(s);

        // slow iff any p >= 0.1  <=>  any 10*e > s (one ballot, wave-uniform)
        if (!__any(10.0f * ml > s)) {
            // ---- fast path: bins {0: 511 elems, 9: target} ----
            nfast += 1u;
            dfast += fmaf(-etb, inv, LOG513);       // ce = ln(513) - p_t
        } else {
            // ---- exact slow path: packed 4-bit x 9 hist + Taylor for s2 ----
            const float ptv = etb * inv;
            unsigned long long hist = 0ull;
            float s2p = 0.0f;
#pragma unroll
            for (int i = 0; i < 8; ++i) {
                float pi = e[i] * inv;
                int b = (int)(pi * 10.0f);
                b = (b > 9) ? 9 : b;
                int isT = (lane == tl) & (i == te);
                hist += (unsigned long long)((b != 0) & !isT) << (((b - 1) & 15) << 2);
                // exp(p)-1-p ~= p^2*(1/2 + p/6 + p^2/24)
                float tq = fmaf(pi, 0.0416666679f, 0.166666672f);
                tq = fmaf(pi, tq, 0.5f);
                s2p = fmaf(pi * pi, tq, s2p);
            }
            if (lane == tl) {
                int bt = (int)((1.0f - ptv) * 10.0f);
                bt = (bt > 9) ? 9 : bt;
                hist += (unsigned long long)(bt != 0) << (((bt - 1) & 15) << 2);
            }
#pragma unroll
            for (int o = 32; o > 0; o >>= 1) {
                hist += __shfl_xor(hist, o);
                s2p  += __shfl_xor(s2p, o);
            }
            if (lane == 0) {
                float ce = __logf(513.0f + s2p) - ptv;
                unsigned int total = 0;
                unsigned int c[9];
#pragma unroll
                for (int b = 0; b < 9; ++b) {
                    c[b] = (unsigned int)((hist >> (4 * b)) & 15ull);
                    total += c[b];
                }
                unsigned int c0 = (unsigned int)CLS - total;
                atomicAdd(&sH[0], c0);
                atomicAdd(&sD[0], (unsigned long long)(long long)(ce * (float)c0 * FXSCALE));
#pragma unroll
                for (int b = 0; b < 9; ++b) {
                    unsigned int cb = c[b];
                    if (cb) {
                        atomicAdd(&sH[b + 1], cb);
                        atomicAdd(&sD[b + 1], (unsigned long long)(long long)(ce * (float)cb * FXSCALE));
                    }
                }
            }
        }

        a0 = a1; b0 = b1;
        a1 = a2; b1 = b2;
    }

    // flush per-wave fast-path accumulators (LDS atomics, cheap)
    if (lane == 0 && nfast) {
        atomicAdd(&sH[0], 511u * nfast);
        atomicAdd(&sH[9], nfast);
        atomicAdd(&sD[0], (unsigned long long)(long long)(dfast * 511.0f * FXSCALE));
        atomicAdd(&sD[9], (unsigned long long)(long long)(dfast * FXSCALE));
    }

    __syncthreads();
    // block epilogue -> slotted global atomics (chain length ~32 per address)
    if (threadIdx.x < NBINS) {
        const int slot = blockIdx.x & (SLOTS - 1);
        unsigned int hc = sH[threadIdx.x];
        unsigned long long dc = sD[threadIdx.x];
        if (hc) atomicAdd(&H[slot * HSTRIDE + threadIdx.x], hc);
        if (dc) atomicAdd(&Dq[slot * DSTRIDE + threadIdx.x], dc);
        __threadfence();   // make this block's adds visible before counting in
    }
    __syncthreads();
    if (threadIdx.x == 0) {
        unsigned int old = atomicAdd(done, 1u);
        isLast = (old == (unsigned int)(gridDim.x - 1)) ? 1 : 0;
    }
    __syncthreads();
    if (!isLast || threadIdx.x >= 64) return;

    // ---- last block, wave 0: reduce 64 slots and write the scalar ----
    __threadfence();
    unsigned int h[NBINS];
    unsigned long long dq[NBINS];
#pragma unroll
    for (int b = 0; b < NBINS; ++b) {
        // atomic fetch-add(0): coherent-point reads (safe across XCD L2s)
        h[b]  = atomicAdd(&H[lane * HSTRIDE + b], 0u);
        dq[b] = atomicAdd(&Dq[lane * DSTRIDE + b], 0ull);
    }
#pragma unroll
    for (int b = 0; b < NBINS; ++b) {
#pragma unroll
        for (int o = 32; o > 0; o >>= 1) {
            h[b]  += __shfl_xor(h[b], o);
            dq[b] += __shfl_xor(dq[b], o);
        }
    }
    if (lane != 0) return;

    int nv = 0;
#pragma unroll
    for (int b = 0; b < NBINS; ++b) nv += (h[b] > 0u) ? 1 : 0;
    float nvf = (float)(nv > 0 ? nv : 1);
    float total = (float)nrows * (float)CLS;  // 2^26, exact in f32

    double loss = 0.0;
    for (int b = 0; b < NBINS; ++b) {
        if (h[b] > 0u) {
            // Reference accumulates counts by serial f32 (+1.0): saturates at 2^24.
            unsigned int hc = h[b];
            if (hc > 16777216u) hc = 16777216u;
            float cf    = (float)hc;
            float acc   = 0.1f * cf;      // (1 - momentum) in f32
            float denom = nvf * acc;
            float w     = total / denom;
            float w75   = powf(w, 0.75f);
            loss += (double)w75 * ((double)dq[b] * (1.0 / 16777216.0));
        }
    }
    out[0] = (float)(loss / ((double)CLS * (double)nrows));
}

extern "C" void kernel_launch(void* const* d_in, const int* in_sizes, int n_in,
                              void* d_out, int out_size, void* d_ws, size_t ws_size,
                              hipStream_t stream) {
    const float* pred   = (const float*)d_in[0];
    const int*   target = (const int*)d_in[1];
    const int    nrows  = in_sizes[1];

    unsigned int*       H    = (unsigned int*)d_ws;
    unsigned long long* Dq   = (unsigned long long*)((char*)d_ws + SLOTS * HSTRIDE * sizeof(unsigned int));
    unsigned int*       done = (unsigned int*)((char*)d_ws + SLOTS * HSTRIDE * sizeof(unsigned int)
                                               + SLOTS * DSTRIDE * sizeof(unsigned long long));
    float*              out  = (float*)d_out;

    hipLaunchKernelGGL(ghm_init_kernel, dim3(1), dim3(256), 0, stream, H, Dq, done);
    int blocks = (nrows + ROWS_PER_BLOCK - 1) / ROWS_PER_BLOCK;
    hipLaunchKernelGGL(ghm_main_kernel, dim3(blocks), dim3(256), 0, stream,
                       pred, target, H, Dq, done, out, nrows);
}

// Round 11
// 59.008 us; speedup vs baseline: 2.0325x; 2.0325x over previous
//
#include <hip/hip_runtime.h>
#include <cstdint>
#include <cstddef>

#define CLS 512
#define NBINS 10
#define ROWS_PER_BLOCK 64      // 4 waves x 16 rows
#define WAVE_ITERS 16          // rows per wave
#define FXSCALE 16777216.0f    // 2^24 fixed-point scale for ce*cnt
#define LOG513 6.2402782f      // ln(513)
#define SLOTS 64               // global histogram copies (atomic spreading)
#define HSTRIDE 32             // u32 per slot (128 B line)
#define DSTRIDE 16             // u64 per slot (128 B line)

// ws layout: [ uint32 H[SLOTS][HSTRIDE] (8 KB) | uint64 Dq[SLOTS][DSTRIDE] (8 KB) ]
//
// Structure note: R7-R10 fused the final reduction into the main kernel via a
// done-counter (last-block-wins). That consistently 2x'd the main kernel
// (59 -> 114-120 us) regardless of launch bounds -- the exit-chain atomic +
// fences + tail code wreck the main loop's load pipeline (latency-bound even
// with L3-resident data). Keep the 3-dispatch structure.

__global__ __launch_bounds__(256) void ghm_init_kernel(unsigned int* __restrict__ H,
                                                       unsigned long long* __restrict__ Dq) {
    for (int k = threadIdx.x; k < SLOTS * HSTRIDE; k += 256) H[k] = 0u;
    for (int k = threadIdx.x; k < SLOTS * DSTRIDE; k += 256) Dq[k] = 0ull;
}

// One wave per row, 16 rows/wave, prefetch depth 2, targets batched up-front.
// No max-subtraction: inputs are N(0,1) (|x| < ~6), so e = exp(x) and
// s = sum(e) are safely finite in f32. Fast path (all p < 0.1, tested via
// one ballot): non-target -> bin 0, target g = 1-p_t -> bin 9, and
// log(sum_i exp(p_i)) = ln(513) + [0, 1.1e-5]. Exact slow path kept.
// NOTE: plain __launch_bounds__(256) ONLY -- a min-waves arg makes the
// scheduler sink the prefetch loads (R8/R9: 2x slower).
__global__ __launch_bounds__(256) void ghm_main_kernel(const float* __restrict__ pred,
                                                       const int* __restrict__ target,
                                                       unsigned int* __restrict__ H,
                                                       unsigned long long* __restrict__ Dq,
                                                       int nrows) {
    __shared__ unsigned int sH[NBINS];
    __shared__ unsigned long long sD[NBINS];
    if (threadIdx.x < NBINS) { sH[threadIdx.x] = 0u; sD[threadIdx.x] = 0ull; }
    __syncthreads();

    const int lane = threadIdx.x & 63;
    const int wid  = threadIdx.x >> 6;
    const int base = blockIdx.x * ROWS_PER_BLOCK;

    // batch this wave's 16 targets: lane k holds iter-k's target
    int tgt_l = 0;
    {
        int idx = base + wid + 4 * lane;
        if (lane < WAVE_ITERS && idx < nrows) tgt_l = target[idx];
    }

    // per-wave fast-path accumulators (flushed once at the end)
    unsigned int nfast = 0u;
    float dfast = 0.0f;

    // prefetch rows k and k+1 (depth 2)
    float4 a0 = make_float4(0.f, 0.f, 0.f, 0.f), b0 = a0;
    float4 a1 = a0, b1 = a0;
    if (base + wid < nrows) {
        const float4* pr = reinterpret_cast<const float4*>(pred + (size_t)(base + wid) * CLS);
        a0 = pr[lane];
        b0 = pr[lane + 64];
    }
    if (base + wid + 4 < nrows) {
        const float4* pr = reinterpret_cast<const float4*>(pred + (size_t)(base + wid + 4) * CLS);
        a1 = pr[lane];
        b1 = pr[lane + 64];
    }

    for (int k = 0; k < WAVE_ITERS; ++k) {
        const int row = base + wid + 4 * k;
        if (row >= nrows) break;

        // issue row k+2's loads before computing on row k
        float4 a2 = make_float4(0.f, 0.f, 0.f, 0.f), b2 = a2;
        if (k + 2 < WAVE_ITERS && row + 8 < nrows) {
            const float4* pn = reinterpret_cast<const float4*>(pred + (size_t)(row + 8) * CLS);
            a2 = pn[lane];
            b2 = pn[lane + 64];
        }

        // direct exp (no max subtraction; inputs N(0,1), |x| < ~6, finite in f32)
        float e[8];
        e[0] = __expf(a0.x); e[1] = __expf(a0.y); e[2] = __expf(a0.z); e[3] = __expf(a0.w);
        e[4] = __expf(b0.x); e[5] = __expf(b0.y); e[6] = __expf(b0.z); e[7] = __expf(b0.w);

        // lane-local sum + max trees (interleaved ILP)
        float s01 = e[0] + e[1], s23 = e[2] + e[3], s45 = e[4] + e[5], s67 = e[6] + e[7];
        float m01 = fmaxf(e[0], e[1]), m23 = fmaxf(e[2], e[3]);
        float m45 = fmaxf(e[4], e[5]), m67 = fmaxf(e[6], e[7]);
        float sl = (s01 + s23) + (s45 + s67);
        float ml = fmaxf(fmaxf(m01, m23), fmaxf(m45, m67));

        const int t  = __builtin_amdgcn_readlane(tgt_l, k);  // wave-uniform
        const int tl = (t & 255) >> 2;                       // owner lane
        const int te = (t & 3) | ((t >> 8) << 2);            // element 0..7 (uniform)

        // target element of e (uniform select), broadcast from owner lane
        float ca = (te & 4)
            ? ((te & 2) ? ((te & 1) ? e[7] : e[6]) : ((te & 1) ? e[5] : e[4]))
            : ((te & 2) ? ((te & 1) ? e[3] : e[2]) : ((te & 1) ? e[1] : e[0]));
        const float etb = __shfl(ca, tl);           // overlaps with sum ladder

        float s = sl;
#pragma unroll
        for (int o = 32; o > 0; o >>= 1) s += __shfl_xor(s, o);
        const float inv = __builtin_amdgcn_rcpf(s);

        // slow iff any p >= 0.1  <=>  any 10*e > s (one ballot, wave-uniform)
        if (!__any(10.0f * ml > s)) {
            // ---- fast path: bins {0: 511 elems, 9: target} ----
            nfast += 1u;
            dfast += fmaf(-etb, inv, LOG513);       // ce = ln(513) - p_t
        } else {
            // ---- exact slow path: packed 4-bit x 9 hist + Taylor for s2 ----
            const float ptv = etb * inv;
            unsigned long long hist = 0ull;
            float s2p = 0.0f;
#pragma unroll
            for (int i = 0; i < 8; ++i) {
                float pi = e[i] * inv;
                int b = (int)(pi * 10.0f);
                b = (b > 9) ? 9 : b;
                int isT = (lane == tl) & (i == te);
                hist += (unsigned long long)((b != 0) & !isT) << (((b - 1) & 15) << 2);
                // exp(p)-1-p ~= p^2*(1/2 + p/6 + p^2/24)
                float tq = fmaf(pi, 0.0416666679f, 0.166666672f);
                tq = fmaf(pi, tq, 0.5f);
                s2p = fmaf(pi * pi, tq, s2p);
            }
            if (lane == tl) {
                int bt = (int)((1.0f - ptv) * 10.0f);
                bt = (bt > 9) ? 9 : bt;
                hist += (unsigned long long)(bt != 0) << (((bt - 1) & 15) << 2);
            }
#pragma unroll
            for (int o = 32; o > 0; o >>= 1) {
                hist += __shfl_xor(hist, o);
                s2p  += __shfl_xor(s2p, o);
            }
            if (lane == 0) {
                float ce = __logf(513.0f + s2p) - ptv;
                unsigned int total = 0;
                unsigned int c[9];
#pragma unroll
                for (int b = 0; b < 9; ++b) {
                    c[b] = (unsigned int)((hist >> (4 * b)) & 15ull);
                    total += c[b];
                }
                unsigned int c0 = (unsigned int)CLS - total;
                atomicAdd(&sH[0], c0);
                atomicAdd(&sD[0], (unsigned long long)(long long)(ce * (float)c0 * FXSCALE));
#pragma unroll
                for (int b = 0; b < 9; ++b) {
                    unsigned int cb = c[b];
                    if (cb) {
                        atomicAdd(&sH[b + 1], cb);
                        atomicAdd(&sD[b + 1], (unsigned long long)(long long)(ce * (float)cb * FXSCALE));
                    }
                }
            }
        }

        a0 = a1; b0 = b1;
        a1 = a2; b1 = b2;
    }

    // flush per-wave fast-path accumulators (LDS atomics, cheap)
    if (lane == 0 && nfast) {
        atomicAdd(&sH[0], 511u * nfast);
        atomicAdd(&sH[9], nfast);
        atomicAdd(&sD[0], (unsigned long long)(long long)(dfast * 511.0f * FXSCALE));
        atomicAdd(&sD[9], (unsigned long long)(long long)(dfast * FXSCALE));
    }

    __syncthreads();
    // block epilogue -> slotted global atomics (chain length ~32 per address)
    if (threadIdx.x < NBINS) {
        const int slot = blockIdx.x & (SLOTS - 1);
        unsigned int hc = sH[threadIdx.x];
        unsigned long long dc = sD[threadIdx.x];
        if (hc) atomicAdd(&H[slot * HSTRIDE + threadIdx.x], hc);
        if (dc) atomicAdd(&Dq[slot * DSTRIDE + threadIdx.x], dc);
    }
}

__global__ __launch_bounds__(64) void ghm_final_kernel(const unsigned int* __restrict__ H,
                                                       const unsigned long long* __restrict__ Dq,
                                                       float* __restrict__ out,
                                                       int nrows) {
    const int lane = threadIdx.x;  // 64 threads, one slot each
    unsigned int h[NBINS];
    unsigned long long dq[NBINS];
#pragma unroll
    for (int b = 0; b < NBINS; ++b) {
        h[b]  = H[lane * HSTRIDE + b];
        dq[b] = Dq[lane * DSTRIDE + b];
    }
#pragma unroll
    for (int b = 0; b < NBINS; ++b) {
#pragma unroll
        for (int o = 32; o > 0; o >>= 1) {
            h[b]  += __shfl_xor(h[b], o);
            dq[b] += __shfl_xor(dq[b], o);
        }
    }
    if (lane != 0) return;

    int nv = 0;
#pragma unroll
    for (int b = 0; b < NBINS; ++b) nv += (h[b] > 0u) ? 1 : 0;
    float nvf = (float)(nv > 0 ? nv : 1);
    float total = (float)nrows * (float)CLS;  // 2^26, exact in f32

    double loss = 0.0;
    for (int b = 0; b < NBINS; ++b) {
        if (h[b] > 0u) {
            // Reference accumulates counts by serial f32 (+1.0): saturates at 2^24.
            unsigned int hc = h[b];
            if (hc > 16777216u) hc = 16777216u;
            float cf    = (float)hc;
            float acc   = 0.1f * cf;      // (1 - momentum) in f32
            float denom = nvf * acc;
            float w     = total / denom;
            float w75   = powf(w, 0.75f);
            loss += (double)w75 * ((double)dq[b] * (1.0 / 16777216.0));
        }
    }
    out[0] = (float)(loss / ((double)CLS * (double)nrows));
}

extern "C" void kernel_launch(void* const* d_in, const int* in_sizes, int n_in,
                              void* d_out, int out_size, void* d_ws, size_t ws_size,
                              hipStream_t stream) {
    const float* pred   = (const float*)d_in[0];
    const int*   target = (const int*)d_in[1];
    const int    nrows  = in_sizes[1];

    unsigned int*       H  = (unsigned int*)d_ws;
    unsigned long long* Dq = (unsigned long long*)((char*)d_ws + SLOTS * HSTRIDE * sizeof(unsigned int));
    float*              out = (float*)d_out;

    hipLaunchKernelGGL(ghm_init_kernel, dim3(1), dim3(256), 0, stream, H, Dq);
    int blocks = (nrows + ROWS_PER_BLOCK - 1) / ROWS_PER_BLOCK;
    hipLaunchKernelGGL(ghm_main_kernel, dim3(blocks), dim3(256), 0, stream,
                       pred, target, H, Dq, nrows);
    hipLaunchKernelGGL(ghm_final_kernel, dim3(1), dim3(64), 0, stream, H, Dq, out, nrows);
}